// Round 3
// baseline (233.087 us; speedup 1.0000x reference)
//
#include <hip/hip_runtime.h>
#include <cstdint>
#include <cstddef>

#define T_SEQ 2048
#define BSZ 4
#define EMB 512
#define NH 8
#define HD 64
#define SCALING 0.125f
#define NEGBIG (-1e30f)
#define KVB 128
#define PW 144   // padded short-row width for Vt/Pl (288B rows: 4-way max on b128 reads)

typedef short bf16x8_t __attribute__((ext_vector_type(8)));
typedef float f32x4_t __attribute__((ext_vector_type(4)));
typedef short short4v __attribute__((ext_vector_type(4)));
typedef float float4v __attribute__((ext_vector_type(4)));

typedef __attribute__((address_space(1))) const void* as1_cvp;
typedef __attribute__((address_space(3))) void* as3_vp;

#define MFMA16(a, b, c) __builtin_amdgcn_mfma_f32_16x16x32_bf16((a), (b), (c), 0, 0, 0)

static __device__ __forceinline__ short f2b(float f) {
  union { float f; uint32_t u; } x; x.f = f;
  uint32_t r = (x.u + 0x7fffu + ((x.u >> 16) & 1u)) >> 16;  // RNE f32->bf16
  return (short)(r & 0xffffu);
}

static __device__ __forceinline__ void gload_lds16(const void* g, void* l) {
  __builtin_amdgcn_global_load_lds((as1_cvp)g, (as3_vp)l, 16, 0, 0);
}

// ---------------------------------------------------------------------------
// f32 -> bf16 conversion
// ---------------------------------------------------------------------------
__global__ __launch_bounds__(256) void cvt_kernel(const float* __restrict__ in,
                                                  short* __restrict__ out) {
  int i = (blockIdx.x * 256 + threadIdx.x) * 4;
  float4v v = *(const float4v*)(in + i);
  short4v o;
  o[0] = f2b(v[0]); o[1] = f2b(v[1]); o[2] = f2b(v[2]); o[3] = f2b(v[3]);
  *(short4v*)(out + i) = o;
}

// ---------------------------------------------------------------------------
// NT bf16 GEMM, 128x128 tile, 4 waves, BK=32, K=512 (validated R1/R2)
// ---------------------------------------------------------------------------
template <int EPI>
__global__ __launch_bounds__(256)
void gemm_bt(const short* __restrict__ A, const short* __restrict__ Bt,
             const float* __restrict__ bias,
             short* __restrict__ outQ, short* __restrict__ outK, short* __restrict__ outV,
             float* __restrict__ outF) {
  __shared__ short ldsA[128 * 32];
  __shared__ short ldsB[128 * 32];
  const int tid = threadIdx.x;
  const int wid = tid >> 6, lane = tid & 63, g = lane >> 4, r16 = lane & 15;
  const int wr = wid >> 1, wc = wid & 1;
  const int mbase = blockIdx.y * 128, nbase = blockIdx.x * 128;

  f32x4_t acc[4][4];
#pragma unroll
  for (int m = 0; m < 4; ++m)
#pragma unroll
    for (int n = 0; n < 4; ++n) acc[m][n] = (f32x4_t){0.f, 0.f, 0.f, 0.f};

  for (int kt = 0; kt < 16; ++kt) {
    __syncthreads();
#pragma unroll
    for (int i = 0; i < 2; ++i) {
      int c = i * 256 + tid;
      int row = c >> 2, j4 = c & 3;
      gload_lds16(A + (size_t)(mbase + row) * 512 + kt * 32 + j4 * 8, &ldsA[c * 8]);
      gload_lds16(Bt + (size_t)(nbase + row) * 512 + kt * 32 + j4 * 8, &ldsB[c * 8]);
    }
    __syncthreads();
    bf16x8_t af[4], bfv[4];
#pragma unroll
    for (int m = 0; m < 4; ++m)
      af[m] = *(const bf16x8_t*)&ldsA[(wr * 64 + m * 16 + r16) * 32 + g * 8];
#pragma unroll
    for (int n = 0; n < 4; ++n)
      bfv[n] = *(const bf16x8_t*)&ldsB[(wc * 64 + n * 16 + r16) * 32 + g * 8];
#pragma unroll
    for (int m = 0; m < 4; ++m)
#pragma unroll
      for (int n = 0; n < 4; ++n) acc[m][n] = MFMA16(af[m], bfv[n], acc[m][n]);
  }

#pragma unroll
  for (int m = 0; m < 4; ++m) {
#pragma unroll
    for (int n = 0; n < 4; ++n) {
      int col = nbase + wc * 64 + n * 16 + r16;
      float bcol = bias[col];
#pragma unroll
      for (int j = 0; j < 4; ++j) {
        int row = mbase + wr * 64 + m * 16 + g * 4 + j;
        float v = acc[m][n][j] + bcol;
        if (EPI == 0) {
          int sect = col >> 9, e = col & 511, hh = e >> 6, d = e & 63;
          int t = row >> 2, b = row & 3;
          size_t dst = ((size_t)(b * NH + hh) * T_SEQ + t) * HD + d;
          short bv = f2b(v);
          if (sect == 0) outQ[dst] = bv;
          else if (sect == 1) outK[dst] = bv;
          else outV[dst] = bv;
        } else {
          outF[(size_t)row * EMB + col] = v;
        }
      }
    }
  }
}

// ---------------------------------------------------------------------------
// Kernel A: partial softmax stats (m,l) per q-row over a key chunk.
// grid (bh, chunk c, qt-desc). Swapped mfma(K,Q): lane owns one q row.
// ---------------------------------------------------------------------------
__global__ __launch_bounds__(256)
void attn_stats(const short* __restrict__ Qg, const short* __restrict__ Kg,
                float2* __restrict__ stats) {
  __shared__ short Kt[KVB * 64];
  const int bh = blockIdx.x, c = blockIdx.y;
  const int qt = 31 - (int)blockIdx.z;
  const int tid = threadIdx.x, wid = tid >> 6, lane = tid & 63;
  const int g = lane >> 4, r16 = lane & 15;
  const size_t headOff = (size_t)bh * T_SEQ * HD;
  const int wrow0 = qt * 64 + wid * 16;
  const int maxcol = qt * 64 + 64;
  const int nkt = (qt >> 1) + 1;
  const int hsp = (nkt + 1) >> 1;
  const int t0 = c ? hsp : 0, t1 = c ? nkt : hsp;
  const int myrow = wrow0 + r16;
  float2* srow = stats + (size_t)(bh * 2 + c) * T_SEQ;

  if (t0 >= t1) {                    // empty chunk: neutral partial
    if (g == 0) srow[myrow] = make_float2(NEGBIG, 0.f);
    return;
  }

  bf16x8_t qf[2];
  {
    const short* qp = Qg + headOff + (size_t)myrow * HD + g * 8;
    qf[0] = *(const bf16x8_t*)qp;
    qf[1] = *(const bf16x8_t*)(qp + 32);
  }

  float m1 = NEGBIG, l1 = 0.f;
  for (int kt = t0; kt < t1; ++kt) {
    const int kb = kt * KVB;
    const int navail = (maxcol - kb) >> 4;
    const int nkc = navail < 8 ? navail : 8;
    __syncthreads();
#pragma unroll
    for (int i = 0; i < 4; ++i) {
      int cc = i * 256 + tid;
      int row = cc >> 3, j8 = (cc & 7) ^ (row & 7);
      gload_lds16(Kg + headOff + (size_t)(kb + row) * HD + j8 * 8, &Kt[cc * 8]);
    }
    __syncthreads();
    float sv[8][4];
#pragma unroll
    for (int kc = 0; kc < 8; ++kc) {
      if (kc < nkc) {
        f32x4_t s = {0.f, 0.f, 0.f, 0.f};
        const int rl = kc * 16 + r16;
#pragma unroll
        for (int kk = 0; kk < 2; ++kk) {
          int byteo = (rl * 128 + kk * 64 + g * 16) ^ ((rl & 7) << 4);
          bf16x8_t kf = *(const bf16x8_t*)((const char*)Kt + byteo);
          s = MFMA16(kf, qf[kk], s);  // swapped: D[key][q]
        }
        const bool nomask = (kb + kc * 16 + 15 <= wrow0);
#pragma unroll
        for (int j = 0; j < 4; ++j) {
          int key = kb + kc * 16 + g * 4 + j;
          sv[kc][j] = (nomask || key <= myrow) ? s[j] * SCALING : NEGBIG;
        }
      }
    }
    float pm = NEGBIG;
#pragma unroll
    for (int kc = 0; kc < 8; ++kc)
      if (kc < nkc) {
#pragma unroll
        for (int j = 0; j < 4; ++j) pm = fmaxf(pm, sv[kc][j]);
      }
    float mn = fmaxf(m1, pm);
    float sum = 0.f;
#pragma unroll
    for (int kc = 0; kc < 8; ++kc)
      if (kc < nkc) {
#pragma unroll
        for (int j = 0; j < 4; ++j) sum += __expf(sv[kc][j] - mn);
      }
    l1 = l1 * __expf(m1 - mn) + sum;
    m1 = mn;
  }
  // merge the 4 lane-groups (lanes r16, +16, +32, +48 share a q row)
#pragma unroll
  for (int off = 16; off <= 32; off <<= 1) {
    float mo = __shfl_xor(m1, off), lo = __shfl_xor(l1, off);
    float mn = fmaxf(m1, mo);
    l1 = l1 * __expf(m1 - mn) + lo * __expf(mo - mn);
    m1 = mn;
  }
  if (g == 0) srow[myrow] = make_float2(m1, l1);
}

// ---------------------------------------------------------------------------
// Kernel B: finalize stats, write normalized P (float4 rows), PV -> O-partial.
// grid (bh, chunk c, qt-desc). Swapped QK^T so each lane owns P row myrow.
// c==1 blocks also zero-fill the strictly-upper P region.
// ---------------------------------------------------------------------------
__global__ __launch_bounds__(256)
void attn_pw(const short* __restrict__ Qg, const short* __restrict__ Kg,
             const short* __restrict__ Vg, const float2* __restrict__ stats,
             float* __restrict__ Pout, float* __restrict__ Opart) {
  __shared__ short Kt[KVB * 64];
  __shared__ short Vt[64 * PW];      // [d][key] pair-packed
  __shared__ short Pl[4][16 * PW];   // per-wave P tile [qlocal][key]
  const int bh = blockIdx.x, c = blockIdx.y;
  const int qt = 31 - (int)blockIdx.z;
  const int tid = threadIdx.x, wid = tid >> 6, lane = tid & 63;
  const int g = lane >> 4, r16 = lane & 15;
  const size_t headOff = (size_t)bh * T_SEQ * HD;
  const int wrow0 = qt * 64 + wid * 16;
  const int maxcol = qt * 64 + 64;
  const int nkt = (qt >> 1) + 1;
  const int hsp = (nkt + 1) >> 1;
  const int t0 = c ? hsp : 0, t1 = c ? nkt : hsp;
  const int myrow = wrow0 + r16;

  // finalize stats for this lane's P row
  float2 s0 = stats[(size_t)(bh * 2 + 0) * T_SEQ + myrow];
  float2 s1 = stats[(size_t)(bh * 2 + 1) * T_SEQ + myrow];
  float mfin = fmaxf(s0.x, s1.x);
  float lfin = s0.y * __expf(s0.x - mfin) + s1.y * __expf(s1.x - mfin);
  float rl2 = 1.0f / lfin;

  f32x4_t oacc[4];
#pragma unroll
  for (int dc = 0; dc < 4; ++dc) oacc[dc] = (f32x4_t){0.f, 0.f, 0.f, 0.f};

  if (t0 < t1) {
    bf16x8_t qf[2];
    {
      const short* qp = Qg + headOff + (size_t)myrow * HD + g * 8;
      qf[0] = *(const bf16x8_t*)qp;
      qf[1] = *(const bf16x8_t*)(qp + 32);
    }
    uint32_t* Vtu = (uint32_t*)Vt;
    for (int kt = t0; kt < t1; ++kt) {
      const int kb = kt * KVB;
      const int navail = (maxcol - kb) >> 4;
      const int nkc = navail < 8 ? navail : 8;
      __syncthreads();
#pragma unroll
      for (int i = 0; i < 4; ++i) {
        int cc = i * 256 + tid;
        int row = cc >> 3, j8 = (cc & 7) ^ (row & 7);
        gload_lds16(Kg + headOff + (size_t)(kb + row) * HD + j8 * 8, &Kt[cc * 8]);
      }
#pragma unroll
      for (int i = 0; i < 2; ++i) {  // V pair-packed transpose staging
        int cc = i * 256 + tid;
        int kp = cc & 63, dg = cc >> 6;
        const short* vp = Vg + headOff + (size_t)(kb + kp * 2) * HD + dg * 8;
        bf16x8_t va = *(const bf16x8_t*)vp;
        bf16x8_t vb = *(const bf16x8_t*)(vp + HD);
#pragma unroll
        for (int j = 0; j < 8; ++j)
          Vtu[(dg * 8 + j) * (PW / 2) + kp] =
              (uint32_t)(uint16_t)va[j] | ((uint32_t)(uint16_t)vb[j] << 16);
      }
      __syncthreads();
#pragma unroll
      for (int kc = 0; kc < 8; ++kc) {
        if (kc < nkc) {
          f32x4_t s = {0.f, 0.f, 0.f, 0.f};
          const int rl = kc * 16 + r16;
#pragma unroll
          for (int kk = 0; kk < 2; ++kk) {
            int byteo = (rl * 128 + kk * 64 + g * 16) ^ ((rl & 7) << 4);
            bf16x8_t kf = *(const bf16x8_t*)((const char*)Kt + byteo);
            s = MFMA16(kf, qf[kk], s);  // swapped: lane owns row myrow
          }
          const int key0 = kb + kc * 16 + g * 4;
          float4v pvv;
          short4v pb;
#pragma unroll
          for (int j = 0; j < 4; ++j) {
            float e = __expf(s[j] * SCALING - mfin) * rl2;
            pvv[j] = (key0 + j <= myrow) ? e : 0.f;
            pb[j] = f2b(pvv[j]);
          }
          *(float4v*)(Pout + ((size_t)bh * T_SEQ + myrow) * T_SEQ + key0) = pvv;
          *(short4v*)&Pl[wid][r16 * PW + kc * 16 + g * 4] = pb;
        }
      }
      // no barrier: Pl is per-wave (lockstep + lgkmcnt), Vt stable till next top barrier
#pragma unroll
      for (int kc2 = 0; kc2 < 4; ++kc2) {
        if (kc2 < (nkc >> 1)) {
          bf16x8_t pf = *(const bf16x8_t*)&Pl[wid][r16 * PW + kc2 * 32 + g * 8];
#pragma unroll
          for (int dc = 0; dc < 4; ++dc) {
            bf16x8_t vf = *(const bf16x8_t*)&Vt[(dc * 16 + r16) * PW + kc2 * 32 + g * 8];
            oacc[dc] = MFMA16(pf, vf, oacc[dc]);
          }
        }
      }
    }
  }

  // O-partial write (zeros for empty chunk keep ws deterministic)
  float* orow = Opart + (size_t)(c * 32 + bh) * T_SEQ * HD;
#pragma unroll
  for (int dc = 0; dc < 4; ++dc) {
#pragma unroll
    for (int j = 0; j < 4; ++j)
      orow[(size_t)(wrow0 + g * 4 + j) * HD + dc * 16 + r16] = oacc[dc][j];
  }

  // zero-fill strictly-upper P region (chunk-1 blocks: big fill <=> few tiles)
  if (c == 1) {
    const int c0 = maxcol;
    const int nc4 = (T_SEQ - c0) >> 2;
    for (int r = 0; r < 64; ++r) {
      size_t base = ((size_t)bh * T_SEQ + qt * 64 + r) * T_SEQ + c0;
      for (int c4 = tid; c4 < nc4; c4 += 256) {
        float4v z = {0.f, 0.f, 0.f, 0.f};
        *(float4v*)(Pout + base + (size_t)c4 * 4) = z;
      }
    }
  }
}

// ---------------------------------------------------------------------------
// Kernel C: sum the two O-partials, convert to bf16 [tok][E] for out-proj GEMM
// ---------------------------------------------------------------------------
__global__ __launch_bounds__(256)
void osum_cvt(const float* __restrict__ Opart, short* __restrict__ aB) {
  int i = (blockIdx.x * 256 + threadIdx.x) * 4;
  int tok = i >> 9, e = i & 511;
  int b = tok & 3, t = tok >> 2, hh = e >> 6, d = e & 63;
  int bh = b * NH + hh;
  size_t o = ((size_t)bh * T_SEQ + t) * HD + d;
  float4v a = *(const float4v*)(Opart + o);
  float4v b4 = *(const float4v*)(Opart + (size_t)32 * T_SEQ * HD + o);
  short4v r;
#pragma unroll
  for (int j = 0; j < 4; ++j) r[j] = f2b(a[j] + b4[j]);
  *(short4v*)(aB + (size_t)tok * EMB + e) = r;
}

// ---------------------------------------------------------------------------
extern "C" void kernel_launch(void* const* d_in, const int* in_sizes, int n_in,
                              void* d_out, int out_size, void* d_ws, size_t ws_size,
                              hipStream_t stream) {
  const float* h = (const float*)d_in[0];
  // d_in[1] = attn_mask (causal, applied structurally)
  const float* w_in = (const float*)d_in[2];
  const float* b_in = (const float*)d_in[3];
  const float* w_out = (const float*)d_in[4];
  const float* b_out = (const float*)d_in[5];
  float* out = (float*)d_out;
  float* Pout = out + (size_t)T_SEQ * BSZ * EMB;

  short* hB = (short*)d_ws;                      // 8192*512 bf16
  short* wB = hB + (size_t)8192 * 512;           // 1536*512
  short* owB = wB + (size_t)1536 * 512;          // 512*512
  short* qB = owB + (size_t)512 * 512;           // 32*2048*64 per-head
  short* kB = qB + (size_t)32 * 2048 * 64;
  short* vB = kB + (size_t)32 * 2048 * 64;
  short* aB = vB + (size_t)32 * 2048 * 64;       // 8192*512
  float2* stats = (float2*)(aB + (size_t)8192 * 512);   // [bh][c][row], 1 MB
  float* Opart = (float*)(stats + (size_t)32 * 2 * T_SEQ);  // [c][bh][row][64], 33.5 MB

  cvt_kernel<<<4096, 256, 0, stream>>>(h, hB);
  cvt_kernel<<<768, 256, 0, stream>>>(w_in, wB);
  cvt_kernel<<<256, 256, 0, stream>>>(w_out, owB);

  gemm_bt<0><<<dim3(12, 64), 256, 0, stream>>>(hB, wB, b_in, qB, kB, vB, nullptr);
  attn_stats<<<dim3(32, 2, 32), 256, 0, stream>>>(qB, kB, stats);
  attn_pw<<<dim3(32, 2, 32), 256, 0, stream>>>(qB, kB, vB, stats, Pout, Opart);
  osum_cvt<<<4096, 256, 0, stream>>>(Opart, aB);
  gemm_bt<1><<<dim3(4, 64), 256, 0, stream>>>(aB, owB, b_out, nullptr, nullptr, nullptr, out);
}